// Round 2
// baseline (1398.869 us; speedup 1.0000x reference)
//
#include <hip/hip_runtime.h>
#include <math.h>

#define TX 32
#define TY 8
#define RPT 8                    // output rows per thread
#define TILE_X TX                // 32 output cols per block
#define TILE_Y (TY * RPT)        // 64 output rows per block
#define IN_X (TILE_X + 10)       // 42 staged cols
#define IN_Y (TILE_Y + 10)       // 74 staged rows
#define HALO 10

// -------------------- fused SSIM-level (+pool) kernel --------------------
// Block: 32x64 output tile of one (b,c) plane. Stage 42x74 inputs in LDS,
// per-thread: horizontal 11-tap into registers per input row, vertical conv
// scatter-accumulated into 8x5 register accumulators (all static indices),
// SSIM pointwise, block reduce, double atomicAdd. Also emits the 2x2
// avg-pooled images for the next level from the staged tile.
__global__ __launch_bounds__(256, 6)
void msssim_level_kernel(const float* __restrict__ img1,
                         const float* __restrict__ img2,
                         int H, int level, double* __restrict__ sums,
                         float* __restrict__ pool1, float* __restrict__ pool2)
{
    __shared__ float sA[IN_Y][IN_X];
    __shared__ float sB[IN_Y][IN_X];
    __shared__ float wred[4][2];

    const int tid = threadIdx.x;
    const int tx = tid & 31;
    const int ty = tid >> 5;

    const int Hout = H - HALO;
    const int oy0 = blockIdx.y * TILE_Y;
    const int ox0 = blockIdx.x * TILE_X;
    const long long base = (long long)blockIdx.z * H * H;

    // ---- Gaussian window in registers (fp32, matches jnp fp32 computation)
    float g[11];
    {
        float s = 0.f;
        #pragma unroll
        for (int i = 0; i < 11; ++i) {
            const float d = (float)(i - 5);
            g[i] = expf(-(d * d) / 4.5f);
            s += g[i];
        }
        #pragma unroll
        for (int i = 0; i < 11; ++i) g[i] /= s;
    }

    // ---- stage 74x42 input tiles as float2 (all offsets even -> aligned)
    for (int w = tid; w < IN_Y * (IN_X / 2); w += 256) {
        const int r = w / (IN_X / 2);
        const int c = 2 * (w % (IN_X / 2));
        const int y = oy0 + r, x = ox0 + c;
        float2 a = make_float2(0.f, 0.f), b = make_float2(0.f, 0.f);
        if (y < H && x < H) {
            const long long idx = base + (long long)y * H + x;
            a = *(const float2*)(img1 + idx);
            b = *(const float2*)(img2 + idx);
        }
        *(float2*)&sA[r][c] = a;
        *(float2*)&sB[r][c] = b;
    }
    __syncthreads();

    // ---- fused 2x2 avg pool for next level (owned region: 64x32 -> 32x16)
    if (pool1 != nullptr) {
        const int Hp = H >> 1;
        for (int w = tid; w < (TILE_Y / 2) * (TILE_X / 2); w += 256) {
            const int pr = w / (TILE_X / 2), pc = w % (TILE_X / 2);
            const int py = (oy0 >> 1) + pr, px = (ox0 >> 1) + pc;
            if (py < Hp && px < Hp) {
                const int r = 2 * pr, c = 2 * pc;
                const float a = 0.25f * (sA[r][c] + sA[r][c + 1] + sA[r + 1][c] + sA[r + 1][c + 1]);
                const float b = 0.25f * (sB[r][c] + sB[r][c + 1] + sB[r + 1][c] + sB[r + 1][c + 1]);
                const long long ob = (long long)blockIdx.z * Hp * Hp + (long long)py * Hp + px;
                pool1[ob] = a;
                pool2[ob] = b;
            }
        }
    }

    // ---- main: horizontal pass per input row (registers), vertical scatter
    float acc[RPT][5];
    #pragma unroll
    for (int o = 0; o < RPT; ++o)
        #pragma unroll
        for (int ch = 0; ch < 5; ++ch) acc[o][ch] = 0.f;

    const int ry0 = ty * RPT;   // thread's first output row (tile-local)
    #pragma unroll
    for (int i = 0; i < RPT + 10; ++i) {
        const int r = ry0 + i;
        float h1 = 0.f, h2 = 0.f, h11 = 0.f, h22 = 0.f, h12 = 0.f;
        #pragma unroll
        for (int k = 0; k < 11; ++k) {
            const float wk = g[k];
            const float x1 = sA[r][tx + k];
            const float x2 = sB[r][tx + k];
            h1  += wk * x1;
            h2  += wk * x2;
            h11 += wk * x1 * x1;
            h22 += wk * x2 * x2;
            h12 += wk * x1 * x2;
        }
        #pragma unroll
        for (int o = 0; o < RPT; ++o) {
            const int kk = i - o;
            if (kk >= 0 && kk <= 10) {   // compile-time resolved
                const float wv = g[kk];
                acc[o][0] += wv * h1;
                acc[o][1] += wv * h2;
                acc[o][2] += wv * h11;
                acc[o][3] += wv * h22;
                acc[o][4] += wv * h12;
            }
        }
    }

    // ---- SSIM pointwise + per-thread accumulate
    const float C1 = 4.0e-4f;   // (0.01*2)^2
    const float C2 = 3.6e-3f;   // (0.03*2)^2
    float ssim_acc = 0.f, cs_acc = 0.f;
    const int ox = ox0 + tx;
    #pragma unroll
    for (int o = 0; o < RPT; ++o) {
        const int oy = oy0 + ry0 + o;
        if (oy < Hout && ox < Hout) {
            const float mu1 = acc[o][0];
            const float mu2 = acc[o][1];
            const float mu1s = mu1 * mu1;
            const float mu2s = mu2 * mu2;
            const float mu12 = mu1 * mu2;
            const float s1  = acc[o][2] - mu1s;
            const float s2  = acc[o][3] - mu2s;
            const float s12 = acc[o][4] - mu12;
            const float v1 = 2.f * s12 + C2;
            const float v2 = s1 + s2 + C2;
            cs_acc   += v1 / v2;
            ssim_acc += ((2.f * mu12 + C1) * v1) / ((mu1s + mu2s + C1) * v2);
        }
    }

    // ---- block reduction
    #pragma unroll
    for (int off = 32; off > 0; off >>= 1) {
        ssim_acc += __shfl_down(ssim_acc, off);
        cs_acc   += __shfl_down(cs_acc, off);
    }
    const int wave = tid >> 6;
    if ((tid & 63) == 0) { wred[wave][0] = ssim_acc; wred[wave][1] = cs_acc; }
    __syncthreads();
    if (tid == 0) {
        const float s = wred[0][0] + wred[1][0] + wred[2][0] + wred[3][0];
        const float c = wred[0][1] + wred[1][1] + wred[2][1] + wred[3][1];
        atomicAdd(&sums[level],     (double)s);
        atomicAdd(&sums[5 + level], (double)c);
    }
}

// -------------------- final combine --------------------
__global__ void msssim_final_kernel(const double* __restrict__ sums,
                                    float* __restrict__ out)
{
    if (threadIdx.x == 0 && blockIdx.x == 0) {
        const double W[5] = {0.0448, 0.2856, 0.3001, 0.2363, 0.1333};
        const int Houts[5] = {502, 246, 118, 54, 22};
        double mssim[5], mcs[5];
        for (int l = 0; l < 5; ++l) {
            const double cnt = 48.0 * (double)Houts[l] * (double)Houts[l];
            mssim[l] = (sums[l]     / cnt + 1.0) * 0.5;
            mcs[l]   = (sums[5 + l] / cnt + 1.0) * 0.5;
        }
        const double p2 = pow(mssim[4], W[4]);
        double prod = 1.0;
        for (int l = 0; l < 4; ++l) prod *= pow(mcs[l], W[l]) * p2;
        out[0] = (float)(1.0 - prod);
    }
}

// -------------------- launch --------------------
extern "C" void kernel_launch(void* const* d_in, const int* in_sizes, int n_in,
                              void* d_out, int out_size, void* d_ws, size_t ws_size,
                              hipStream_t stream)
{
    const float* img1 = (const float*)d_in[0];
    const float* img2 = (const float*)d_in[1];
    float* out = (float*)d_out;
    (void)in_sizes; (void)n_in; (void)out_size; (void)ws_size;

    char* ws = (char*)d_ws;
    double* sums = (double*)ws;                      // 10 doubles
    float* X1 = (float*)(ws + 256);                  // 3,145,728 floats
    float* X2 = X1 + 3145728;
    float* Y1 = X2 + 3145728;                        // 786,432 floats
    float* Y2 = Y1 + 786432;

    hipMemsetAsync(sums, 0, 10 * sizeof(double), stream);

    auto launch_level = [&](const float* a, const float* b, int H, int level,
                            float* pa, float* pb) {
        const int Hout = H - HALO;
        const int xt = (Hout + TILE_X - 1) / TILE_X;
        const int yt = (Hout + TILE_Y - 1) / TILE_Y;
        dim3 grid(xt, yt, 48);
        hipLaunchKernelGGL(msssim_level_kernel, grid, dim3(256), 0, stream,
                           a, b, H, level, sums, pa, pb);
    };

    launch_level(img1, img2, 512, 0, X1, X2);   // level 0, pool -> X (256)
    launch_level(X1, X2, 256, 1, Y1, Y2);       // level 1, pool -> Y (128)
    launch_level(Y1, Y2, 128, 2, X1, X2);       // level 2, pool -> X (64)
    launch_level(X1, X2, 64, 3, Y1, Y2);        // level 3, pool -> Y (32)
    launch_level(Y1, Y2, 32, 4, nullptr, nullptr); // level 4

    hipLaunchKernelGGL(msssim_final_kernel, dim3(1), dim3(64), 0, stream, sums, out);
}